// Round 3
// baseline (1236.715 us; speedup 1.0000x reference)
//
#include <hip/hip_runtime.h>
#include <hip/hip_bf16.h>

#define B_ 4
#define T_ 4096
#define C_ 1024
#define H_ 64

// ============================================================================
// Projection GEMM: out[M=B*T][64] = x[M][C] @ W[C][64], one W per blockIdx.y
// BM=64, BN=64, BK=32, 256 threads, 4x4 micro-tile per thread. (unchanged)
// ============================================================================
__global__ __launch_bounds__(256, 4)
void proj_kernel(const float* __restrict__ x,
                 const float* __restrict__ Wq,
                 const float* __restrict__ Wk,
                 const float* __restrict__ Wv,
                 float* __restrict__ q, float* __restrict__ k, float* __restrict__ v)
{
    __shared__ __align__(16) float As[32][68];
    __shared__ __align__(16) float Bs[32][64];

    const int m0  = blockIdx.x * 64;
    const int mat = blockIdx.y;
    const float* W  = (mat == 0) ? Wq : (mat == 1) ? Wk : Wv;
    float* out      = (mat == 0) ? q  : (mat == 1) ? k  : v;

    const int tid = threadIdx.x;
    const int tx  = tid & 15;
    const int ty  = tid >> 4;

    float acc[4][4];
    #pragma unroll
    for (int i = 0; i < 4; ++i)
        #pragma unroll
        for (int j = 0; j < 4; ++j) acc[i][j] = 0.f;

    for (int k0 = 0; k0 < C_; k0 += 32) {
        #pragma unroll
        for (int i = 0; i < 2; ++i) {
            int f   = tid + i * 256;
            int row = f >> 3;
            int kc4 = f & 7;
            float4 a = *(const float4*)&x[(size_t)(m0 + row) * C_ + k0 + kc4 * 4];
            As[kc4 * 4 + 0][row] = a.x;
            As[kc4 * 4 + 1][row] = a.y;
            As[kc4 * 4 + 2][row] = a.z;
            As[kc4 * 4 + 3][row] = a.w;
        }
        #pragma unroll
        for (int i = 0; i < 2; ++i) {
            int f   = tid + i * 256;
            int row = f >> 4;
            int c4  = f & 15;
            *(float4*)&Bs[row][c4 * 4] = *(const float4*)&W[(size_t)(k0 + row) * H_ + c4 * 4];
        }
        __syncthreads();

        #pragma unroll
        for (int kk = 0; kk < 32; ++kk) {
            float4 a = *(const float4*)&As[kk][ty * 4];
            float4 b = *(const float4*)&Bs[kk][tx * 4];
            float av[4] = {a.x, a.y, a.z, a.w};
            float bv[4] = {b.x, b.y, b.z, b.w};
            #pragma unroll
            for (int i = 0; i < 4; ++i)
                #pragma unroll
                for (int j = 0; j < 4; ++j)
                    acc[i][j] = fmaf(av[i], bv[j], acc[i][j]);
        }
        __syncthreads();
    }

    #pragma unroll
    for (int i = 0; i < 4; ++i) {
        float4 st = make_float4(acc[i][0], acc[i][1], acc[i][2], acc[i][3]);
        *(float4*)&out[(size_t)(m0 + ty * 4 + i) * H_ + tx * 4] = st;
    }
}

// ============================================================================
// Flash attention (causal), fp32. 16-row q-tiles, 16 key-splits, KT=4 keys
// per split-iteration staged in LDS (broadcast reads). 1024 blocks, all
// co-resident (4 blocks/CU = 16 waves/CU). Per-CU work equalized via the
// {a, 127-a, 128+a, 255-a} tile grouping. Split s takes 4-key tiles
// s, s+16, s+32... so splits hit the causal cutoff together.
// LDS: K,V = 2*16*264 floats (split stride 264 = bank-offset 8 per split),
// merge tree needs 8960 floats -> 35840 B total -> 4 blocks/CU.
// ============================================================================
#define ROWS    16
#define SPLITS  16
#define KT      4
#define KSTRIDE 264   // KT*64 + 8 pad: consecutive splits 8 banks apart

__global__ __launch_bounds__(256, 4)
void attn_kernel(const float* __restrict__ Q, const float* __restrict__ K,
                 const float* __restrict__ V, float* __restrict__ out)
{
    __shared__ __align__(16) float lds[8960];   // 35840 B
    float* KsBase = lds;                         // [split] stride KSTRIDE
    float* VsBase = lds + SPLITS * KSTRIDE;      // 4224 floats each

    const int bx = blockIdx.x;
    const int v_ = bx >> 8;          // 0..3
    const int u  = bx & 255;
    const int b  = u & 3;
    const int a  = u >> 2;           // 0..63
    // per-CU-group equalized tiles: a, 127-a, 128+a, 255-a (sum 510)
    const int tile = (v_ == 0) ? a : (v_ == 1) ? (127 - a)
                   : (v_ == 2) ? (128 + a) : (255 - a);
    const int t0   = tile * ROWS;

    const int tid   = threadIdx.x;
    const int r     = tid & 15;      // q row within tile
    const int split = tid >> 4;      // key split 0..15
    const int t     = t0 + r;        // my q row

    const float* Qrow = Q + ((size_t)b * T_ + t) * H_;
    float4 q4[16];
    #pragma unroll
    for (int d = 0; d < 16; ++d) q4[d] = ((const float4*)Qrow)[d];

    float4 o4[16];
    #pragma unroll
    for (int d = 0; d < 16; ++d) o4[d] = make_float4(0.f, 0.f, 0.f, 0.f);
    float m = -1e30f, l = 0.f;

    const float* Kb = K + (size_t)b * T_ * H_;
    const float* Vb = V + (size_t)b * T_ * H_;

    float* Ks = KsBase + split * KSTRIDE;
    float* Vs = VsBase + split * KSTRIDE;

    const int nt4   = 4 * (tile + 1);             // 4-key tiles needed
    const int itmax = (nt4 + SPLITS - 1) / SPLITS;

    for (int it = 0; it < itmax; ++it) {
        const int  tidx = it * SPLITS + split;
        const bool act  = (tidx < nt4);
        const int  j0   = tidx * KT;

        __syncthreads();   // previous iteration's compute done before overwrite
        if (act) {
            const float4* Kg = (const float4*)(Kb + (size_t)j0 * H_);
            const float4* Vg = (const float4*)(Vb + (size_t)j0 * H_);
            float4* KsD = (float4*)Ks;
            float4* VsD = (float4*)Vs;
            #pragma unroll
            for (int i = 0; i < 4; ++i) {      // KT*64 = 256 floats = 64 f4
                int f = r + i * 16;
                KsD[f] = Kg[f];
                VsD[f] = Vg[f];
            }
        }
        __syncthreads();

        if (act && j0 <= t) {
            float s_arr[KT];
            #pragma unroll
            for (int j = 0; j < KT; ++j) {
                const float4* Kj = (const float4*)&Ks[j * 64];
                float a0 = 0.f, a1 = 0.f, a2 = 0.f, a3 = 0.f;
                #pragma unroll
                for (int d = 0; d < 16; ++d) {
                    float4 kk = Kj[d];
                    a0 = fmaf(q4[d].x, kk.x, a0);
                    a1 = fmaf(q4[d].y, kk.y, a1);
                    a2 = fmaf(q4[d].z, kk.z, a2);
                    a3 = fmaf(q4[d].w, kk.w, a3);
                }
                float sj = (a0 + a1) + (a2 + a3);
                s_arr[j] = (j0 + j <= t) ? sj * 0.125f : -1e30f;
            }

            float tmax = s_arr[0];
            #pragma unroll
            for (int j = 1; j < KT; ++j) tmax = fmaxf(tmax, s_arr[j]);
            float mnew = fmaxf(m, tmax);
            float sc = __expf(m - mnew);
            l *= sc;
            #pragma unroll
            for (int d = 0; d < 16; ++d) {
                o4[d].x *= sc; o4[d].y *= sc; o4[d].z *= sc; o4[d].w *= sc;
            }

            #pragma unroll
            for (int j = 0; j < KT; ++j) {
                float pj = __expf(s_arr[j] - mnew);
                l += pj;
                const float4* Vj = (const float4*)&Vs[j * 64];
                #pragma unroll
                for (int d = 0; d < 16; ++d) {
                    float4 vv = Vj[d];
                    o4[d].x = fmaf(pj, vv.x, o4[d].x);
                    o4[d].y = fmaf(pj, vv.y, o4[d].y);
                    o4[d].z = fmaf(pj, vv.z, o4[d].z);
                    o4[d].w = fmaf(pj, vv.w, o4[d].w);
                }
            }
            m = mnew;
        }
    }

    // ---- merge the 16 splits per row: 4-step tree through LDS ----
    // Reuse lds: mo[slot][68], slot = (split-step)*16 + r, ml after 128*68.
    float* mo = lds;
    float* ml = lds + 128 * 68;

    #pragma unroll
    for (int step = 8; step >= 1; step >>= 1) {
        __syncthreads();
        if (split >= step && split < 2 * step) {
            int slot = (split - step) * ROWS + r;
            #pragma unroll
            for (int d = 0; d < 16; ++d)
                *(float4*)&mo[slot * 68 + d * 4] = o4[d];
            ml[slot * 2 + 0] = m;
            ml[slot * 2 + 1] = l;
        }
        __syncthreads();
        if (split < step) {
            int slot = split * ROWS + r;
            float m2 = ml[slot * 2 + 0];
            float l2 = ml[slot * 2 + 1];
            float M  = fmaxf(m, m2);
            float w1 = __expf(m - M);    // both empty (-1e30): w=1, l stays 0
            float w2 = __expf(m2 - M);
            l = w1 * l + w2 * l2;
            #pragma unroll
            for (int d = 0; d < 16; ++d) {
                float4 o2 = *(const float4*)&mo[slot * 68 + d * 4];
                o4[d].x = w1 * o4[d].x + w2 * o2.x;
                o4[d].y = w1 * o4[d].y + w2 * o2.y;
                o4[d].z = w1 * o4[d].z + w2 * o2.z;
                o4[d].w = w1 * o4[d].w + w2 * o2.w;
            }
            m = M;
        }
    }

    if (split == 0) {
        float inv = 1.0f / l;            // key 0 always present: l > 0
        float* orow = out + ((size_t)b * T_ + t) * H_;
        #pragma unroll
        for (int d = 0; d < 16; ++d) {
            float4 o = o4[d];
            o.x *= inv; o.y *= inv; o.z *= inv; o.w *= inv;
            ((float4*)orow)[d] = o;
        }
    }
}

extern "C" void kernel_launch(void* const* d_in, const int* in_sizes, int n_in,
                              void* d_out, int out_size, void* d_ws, size_t ws_size,
                              hipStream_t stream) {
    const float* x  = (const float*)d_in[0];
    const float* Wq = (const float*)d_in[1];
    const float* Wk = (const float*)d_in[2];
    const float* Wv = (const float*)d_in[3];
    float* out = (float*)d_out;

    const size_t BTH = (size_t)B_ * T_ * H_;
    float* q = (float*)d_ws;
    float* k = q + BTH;
    float* v = k + BTH;

    dim3 gp(B_ * T_ / 64, 3);
    proj_kernel<<<gp, 256, 0, stream>>>(x, Wq, Wk, Wv, q, k, v);

    attn_kernel<<<1024, 256, 0, stream>>>(q, k, v, out);
}

// Round 4
// 438.405 us; speedup vs baseline: 2.8209x; 2.8209x over previous
//
#include <hip/hip_runtime.h>
#include <hip/hip_bf16.h>

#define B_ 4
#define T_ 4096
#define C_ 1024
#define H_ 64

typedef _Float16 half4_t __attribute__((ext_vector_type(4)));
typedef _Float16 half8_t __attribute__((ext_vector_type(8)));
typedef float    f32x4   __attribute__((ext_vector_type(4)));

// ============================================================================
// split_w: Wq/Wk/Wv fp32 [1024][64] -> f16 hi/lo in fragment-major layout
// Wf[mat][kk8 (k/8)][nm (0..63)][i (k%8)], 196608 halfs per array.
// ============================================================================
__global__ void split_w_kernel(const float* __restrict__ Wq,
                               const float* __restrict__ Wk,
                               const float* __restrict__ Wv,
                               _Float16* __restrict__ Wf_hi,
                               _Float16* __restrict__ Wf_lo)
{
    int g = blockIdx.x * 256 + threadIdx.x;     // 0..24575
    int nm  = g & 63;
    int kk8 = (g >> 6) & 127;
    int mat = g >> 13;                          // 0..2
    const float* W = (mat == 0) ? Wq : (mat == 1) ? Wk : Wv;

    half8_t hi, lo;
    #pragma unroll
    for (int i = 0; i < 8; ++i) {
        float w = W[(kk8 * 8 + i) * 64 + nm];
        _Float16 h = (_Float16)w;
        float r = w - (float)h;
        hi[i] = h;
        lo[i] = (_Float16)r;
    }
    ((half8_t*)Wf_hi)[g] = hi;
    ((half8_t*)Wf_lo)[g] = lo;
}

// ============================================================================
// proj_mfma: out[16384][64] = x @ W via f16x3 MFMA (hi*hi + hi*lo + lo*hi).
// BM=64, BK=64, one mat per blockIdx.y. 256 threads = 4 waves, 2x2 wave grid,
// each wave 32x32 out = 2x2 frags of mfma_f32_16x16x32_f16.
// LDS: Ah/Al 64x72 halfs (row pad 72 -> 144 B, bank-safe), Bh/Bl 4096 halfs
// (fragment-major, straight copy from pre-split W). 53 KB -> 3 blocks/CU,
// grid 768 = exactly 3/CU.
// Fragment layouts (gfx950 16x16x32): A: row=lane&15, k=(lane>>4)*8+i;
// B: col=lane&15, k=(lane>>4)*8+i; C/D: col=lane&15, row=(lane>>4)*4+reg
// (C/D HW-verified per guide m89; dtype-independent).
// ============================================================================
__global__ __launch_bounds__(256, 2)
void proj_mfma_kernel(const float* __restrict__ x,
                      const _Float16* __restrict__ Wf_hi,
                      const _Float16* __restrict__ Wf_lo,
                      float* __restrict__ q, float* __restrict__ k,
                      float* __restrict__ v)
{
    __shared__ __align__(16) _Float16 Ah[64 * 72];
    __shared__ __align__(16) _Float16 Al[64 * 72];
    __shared__ __align__(16) _Float16 Bh[4096];
    __shared__ __align__(16) _Float16 Bl[4096];

    const int tid  = threadIdx.x;
    const int lane = tid & 63;
    const int wid  = tid >> 6;
    const int wm   = wid >> 1;          // 0..1
    const int wn   = wid & 1;           // 0..1
    const int l15  = lane & 15;
    const int lg   = lane >> 4;         // 0..3

    const int m0  = blockIdx.x * 64;
    const int mat = blockIdx.y;
    float* out = (mat == 0) ? q : (mat == 1) ? k : v;
    const _Float16* WfhM = Wf_hi + mat * 65536;
    const _Float16* WflM = Wf_lo + mat * 65536;

    f32x4 accM[2][2], accC[2][2];
    #pragma unroll
    for (int a = 0; a < 2; ++a)
        #pragma unroll
        for (int b = 0; b < 2; ++b) {
            accM[a][b] = (f32x4){0.f, 0.f, 0.f, 0.f};
            accC[a][b] = (f32x4){0.f, 0.f, 0.f, 0.f};
        }

    for (int kstep = 0; kstep < 16; ++kstep) {
        const int k0 = kstep * 64;
        __syncthreads();
        // ---- stage x tile (64 rows x 64 k) -> Ah/Al ----
        #pragma unroll
        for (int j = 0; j < 4; ++j) {
            int f   = tid + j * 256;        // 0..1023
            int row = f >> 4;
            int c4  = f & 15;
            float4 xv = *(const float4*)&x[(size_t)(m0 + row) * C_ + k0 + c4 * 4];
            _Float16 hx = (_Float16)xv.x; _Float16 lx = (_Float16)(xv.x - (float)hx);
            _Float16 hy = (_Float16)xv.y; _Float16 ly = (_Float16)(xv.y - (float)hy);
            _Float16 hz = (_Float16)xv.z; _Float16 lz = (_Float16)(xv.z - (float)hz);
            _Float16 hw = (_Float16)xv.w; _Float16 lw = (_Float16)(xv.w - (float)hw);
            int off = row * 72 + c4 * 4;
            *(half4_t*)&Ah[off] = (half4_t){hx, hy, hz, hw};
            *(half4_t*)&Al[off] = (half4_t){lx, ly, lz, lw};
        }
        // ---- stage W slice (8 KB each half), straight copy ----
        {
            const uint4* gh = (const uint4*)(WfhM + kstep * 4096);
            const uint4* gl = (const uint4*)(WflM + kstep * 4096);
            #pragma unroll
            for (int j = 0; j < 2; ++j) {
                int f = tid + j * 256;      // 0..511 (16 B units)
                *(uint4*)&Bh[f * 8] = gh[f];
                *(uint4*)&Bl[f * 8] = gl[f];
            }
        }
        __syncthreads();

        // ---- compute: 2 k-slices of 32 ----
        #pragma unroll
        for (int ks = 0; ks < 2; ++ks) {
            half8_t ah[2], al[2], bh[2], bl[2];
            #pragma unroll
            for (int fm = 0; fm < 2; ++fm) {
                int off = (wm * 32 + fm * 16 + l15) * 72 + ks * 32 + lg * 8;
                ah[fm] = *(const half8_t*)&Ah[off];
                al[fm] = *(const half8_t*)&Al[off];
            }
            #pragma unroll
            for (int fn = 0; fn < 2; ++fn) {
                int kk8l = ks * 4 + lg;
                int n    = wn * 32 + fn * 16 + l15;
                int off  = (kk8l * 64 + n) * 8;
                bh[fn] = *(const half8_t*)&Bh[off];
                bl[fn] = *(const half8_t*)&Bl[off];
            }
            #pragma unroll
            for (int fm = 0; fm < 2; ++fm)
                #pragma unroll
                for (int fn = 0; fn < 2; ++fn) {
                    accM[fm][fn] = __builtin_amdgcn_mfma_f32_16x16x32_f16(
                        ah[fm], bh[fn], accM[fm][fn], 0, 0, 0);
                    accC[fm][fn] = __builtin_amdgcn_mfma_f32_16x16x32_f16(
                        ah[fm], bl[fn], accC[fm][fn], 0, 0, 0);
                    accC[fm][fn] = __builtin_amdgcn_mfma_f32_16x16x32_f16(
                        al[fm], bh[fn], accC[fm][fn], 0, 0, 0);
                }
        }
    }

    // ---- write out: C/D col=lane&15, row=(lane>>4)*4+reg ----
    #pragma unroll
    for (int fm = 0; fm < 2; ++fm)
        #pragma unroll
        for (int fn = 0; fn < 2; ++fn) {
            int col = wn * 32 + fn * 16 + l15;
            int rw0 = m0 + wm * 32 + fm * 16 + lg * 4;
            #pragma unroll
            for (int reg = 0; reg < 4; ++reg) {
                float val = accM[fm][fn][reg] + accC[fm][fn][reg];
                out[(size_t)(rw0 + reg) * H_ + col] = val;
            }
        }
}

// ============================================================================
// Fallback fp32 projection (known-good), used only if ws_size is too small.
// ============================================================================
__global__ __launch_bounds__(256, 4)
void proj_kernel(const float* __restrict__ x,
                 const float* __restrict__ Wq,
                 const float* __restrict__ Wk,
                 const float* __restrict__ Wv,
                 float* __restrict__ q, float* __restrict__ k, float* __restrict__ v)
{
    __shared__ __align__(16) float As[32][68];
    __shared__ __align__(16) float Bs[32][64];

    const int m0  = blockIdx.x * 64;
    const int mat = blockIdx.y;
    const float* W  = (mat == 0) ? Wq : (mat == 1) ? Wk : Wv;
    float* out      = (mat == 0) ? q  : (mat == 1) ? k  : v;

    const int tid = threadIdx.x;
    const int tx  = tid & 15;
    const int ty  = tid >> 4;

    float acc[4][4];
    #pragma unroll
    for (int i = 0; i < 4; ++i)
        #pragma unroll
        for (int j = 0; j < 4; ++j) acc[i][j] = 0.f;

    for (int k0 = 0; k0 < C_; k0 += 32) {
        #pragma unroll
        for (int i = 0; i < 2; ++i) {
            int f   = tid + i * 256;
            int row = f >> 3;
            int kc4 = f & 7;
            float4 a = *(const float4*)&x[(size_t)(m0 + row) * C_ + k0 + kc4 * 4];
            As[kc4 * 4 + 0][row] = a.x;
            As[kc4 * 4 + 1][row] = a.y;
            As[kc4 * 4 + 2][row] = a.z;
            As[kc4 * 4 + 3][row] = a.w;
        }
        #pragma unroll
        for (int i = 0; i < 2; ++i) {
            int f   = tid + i * 256;
            int row = f >> 4;
            int c4  = f & 15;
            *(float4*)&Bs[row][c4 * 4] = *(const float4*)&W[(size_t)(k0 + row) * H_ + c4 * 4];
        }
        __syncthreads();

        #pragma unroll
        for (int kk = 0; kk < 32; ++kk) {
            float4 a = *(const float4*)&As[kk][ty * 4];
            float4 b = *(const float4*)&Bs[kk][tx * 4];
            float av[4] = {a.x, a.y, a.z, a.w};
            float bv[4] = {b.x, b.y, b.z, b.w};
            #pragma unroll
            for (int i = 0; i < 4; ++i)
                #pragma unroll
                for (int j = 0; j < 4; ++j)
                    acc[i][j] = fmaf(av[i], bv[j], acc[i][j]);
        }
        __syncthreads();
    }

    #pragma unroll
    for (int i = 0; i < 4; ++i) {
        float4 st = make_float4(acc[i][0], acc[i][1], acc[i][2], acc[i][3]);
        *(float4*)&out[(size_t)(m0 + ty * 4 + i) * H_ + tx * 4] = st;
    }
}

// ============================================================================
// Flash attention (causal), fp32. R3 structure (balanced tiles, 16 splits,
// KT=4, 35 KB LDS) with R2's launch bounds: (256,2) -> 128 VGPR, no spill.
// ============================================================================
#define ROWS    16
#define SPLITS  16
#define KT      4
#define KSTRIDE 264

__global__ __launch_bounds__(256, 2)
void attn_kernel(const float* __restrict__ Q, const float* __restrict__ K,
                 const float* __restrict__ V, float* __restrict__ out)
{
    __shared__ __align__(16) float lds[8960];
    float* KsBase = lds;
    float* VsBase = lds + SPLITS * KSTRIDE;

    const int bx = blockIdx.x;
    const int v_ = bx >> 8;
    const int u  = bx & 255;
    const int b  = u & 3;
    const int a  = u >> 2;
    const int tile = (v_ == 0) ? a : (v_ == 1) ? (127 - a)
                   : (v_ == 2) ? (128 + a) : (255 - a);
    const int t0   = tile * ROWS;

    const int tid   = threadIdx.x;
    const int r     = tid & 15;
    const int split = tid >> 4;
    const int t     = t0 + r;

    const float* Qrow = Q + ((size_t)b * T_ + t) * H_;
    float4 q4[16];
    #pragma unroll
    for (int d = 0; d < 16; ++d) q4[d] = ((const float4*)Qrow)[d];

    float4 o4[16];
    #pragma unroll
    for (int d = 0; d < 16; ++d) o4[d] = make_float4(0.f, 0.f, 0.f, 0.f);
    float m = -1e30f, l = 0.f;

    const float* Kb = K + (size_t)b * T_ * H_;
    const float* Vb = V + (size_t)b * T_ * H_;

    float* Ks = KsBase + split * KSTRIDE;
    float* Vs = VsBase + split * KSTRIDE;

    const int nt4   = 4 * (tile + 1);
    const int itmax = (nt4 + SPLITS - 1) / SPLITS;

    for (int it = 0; it < itmax; ++it) {
        const int  tidx = it * SPLITS + split;
        const bool act  = (tidx < nt4);
        const int  j0   = tidx * KT;

        __syncthreads();
        if (act) {
            const float4* Kg = (const float4*)(Kb + (size_t)j0 * H_);
            const float4* Vg = (const float4*)(Vb + (size_t)j0 * H_);
            float4* KsD = (float4*)Ks;
            float4* VsD = (float4*)Vs;
            #pragma unroll
            for (int i = 0; i < 4; ++i) {
                int f = r + i * 16;
                KsD[f] = Kg[f];
                VsD[f] = Vg[f];
            }
        }
        __syncthreads();

        if (act && j0 <= t) {
            float s_arr[KT];
            #pragma unroll
            for (int j = 0; j < KT; ++j) {
                const float4* Kj = (const float4*)&Ks[j * 64];
                float a0 = 0.f, a1 = 0.f, a2 = 0.f, a3 = 0.f;
                #pragma unroll
                for (int d = 0; d < 16; ++d) {
                    float4 kk = Kj[d];
                    a0 = fmaf(q4[d].x, kk.x, a0);
                    a1 = fmaf(q4[d].y, kk.y, a1);
                    a2 = fmaf(q4[d].z, kk.z, a2);
                    a3 = fmaf(q4[d].w, kk.w, a3);
                }
                float sj = (a0 + a1) + (a2 + a3);
                s_arr[j] = (j0 + j <= t) ? sj * 0.125f : -1e30f;
            }

            float tmax = s_arr[0];
            #pragma unroll
            for (int j = 1; j < KT; ++j) tmax = fmaxf(tmax, s_arr[j]);
            float mnew = fmaxf(m, tmax);
            float sc = __expf(m - mnew);
            l *= sc;
            #pragma unroll
            for (int d = 0; d < 16; ++d) {
                o4[d].x *= sc; o4[d].y *= sc; o4[d].z *= sc; o4[d].w *= sc;
            }

            #pragma unroll
            for (int j = 0; j < KT; ++j) {
                float pj = __expf(s_arr[j] - mnew);
                l += pj;
                const float4* Vj = (const float4*)&Vs[j * 64];
                #pragma unroll
                for (int d = 0; d < 16; ++d) {
                    float4 vv = Vj[d];
                    o4[d].x = fmaf(pj, vv.x, o4[d].x);
                    o4[d].y = fmaf(pj, vv.y, o4[d].y);
                    o4[d].z = fmaf(pj, vv.z, o4[d].z);
                    o4[d].w = fmaf(pj, vv.w, o4[d].w);
                }
            }
            m = mnew;
        }
    }

    float* mo = lds;
    float* ml = lds + 128 * 68;

    #pragma unroll
    for (int step = 8; step >= 1; step >>= 1) {
        __syncthreads();
        if (split >= step && split < 2 * step) {
            int slot = (split - step) * ROWS + r;
            #pragma unroll
            for (int d = 0; d < 16; ++d)
                *(float4*)&mo[slot * 68 + d * 4] = o4[d];
            ml[slot * 2 + 0] = m;
            ml[slot * 2 + 1] = l;
        }
        __syncthreads();
        if (split < step) {
            int slot = split * ROWS + r;
            float m2 = ml[slot * 2 + 0];
            float l2 = ml[slot * 2 + 1];
            float M  = fmaxf(m, m2);
            float w1 = __expf(m - M);
            float w2 = __expf(m2 - M);
            l = w1 * l + w2 * l2;
            #pragma unroll
            for (int d = 0; d < 16; ++d) {
                float4 o2 = *(const float4*)&mo[slot * 68 + d * 4];
                o4[d].x = w1 * o4[d].x + w2 * o2.x;
                o4[d].y = w1 * o4[d].y + w2 * o2.y;
                o4[d].z = w1 * o4[d].z + w2 * o2.z;
                o4[d].w = w1 * o4[d].w + w2 * o2.w;
            }
            m = M;
        }
    }

    if (split == 0) {
        float inv = 1.0f / l;
        float* orow = out + ((size_t)b * T_ + t) * H_;
        #pragma unroll
        for (int d = 0; d < 16; ++d) {
            float4 o = o4[d];
            o.x *= inv; o.y *= inv; o.z *= inv; o.w *= inv;
            ((float4*)orow)[d] = o;
        }
    }
}

extern "C" void kernel_launch(void* const* d_in, const int* in_sizes, int n_in,
                              void* d_out, int out_size, void* d_ws, size_t ws_size,
                              hipStream_t stream) {
    const float* x  = (const float*)d_in[0];
    const float* Wq = (const float*)d_in[1];
    const float* Wk = (const float*)d_in[2];
    const float* Wv = (const float*)d_in[3];
    float* out = (float*)d_out;

    const size_t BTH = (size_t)B_ * T_ * H_;
    float* q = (float*)d_ws;
    float* k = q + BTH;
    float* v = k + BTH;

    const size_t need = BTH * 3 * sizeof(float) + 2 * 196608 * sizeof(_Float16);
    if (ws_size >= need) {
        _Float16* Wf_hi = (_Float16*)(v + BTH);
        _Float16* Wf_lo = Wf_hi + 196608;
        split_w_kernel<<<96, 256, 0, stream>>>(Wq, Wk, Wv, Wf_hi, Wf_lo);
        dim3 gp(B_ * T_ / 64, 3);
        proj_mfma_kernel<<<gp, 256, 0, stream>>>(x, Wf_hi, Wf_lo, q, k, v);
    } else {
        dim3 gp(B_ * T_ / 64, 3);
        proj_kernel<<<gp, 256, 0, stream>>>(x, Wq, Wk, Wv, q, k, v);
    }

    attn_kernel<<<1024, 256, 0, stream>>>(q, k, v, out);
}

// Round 13
// 175.045 us; speedup vs baseline: 7.0651x; 2.5045x over previous
//
#include <hip/hip_runtime.h>
#include <hip/hip_bf16.h>

#define B_ 4
#define T_ 4096
#define C_ 1024
#define H_ 64

typedef _Float16 half4_t __attribute__((ext_vector_type(4)));
typedef _Float16 half8_t __attribute__((ext_vector_type(8)));
typedef float    f32x4   __attribute__((ext_vector_type(4)));

// ============================================================================
// split_w: Wq/Wk/Wv fp32 [1024][64] -> f16 hi/lo in fragment-major layout
// Wf[mat][kk8][nm][i], 196608 halfs per array. (validated R4)
// ============================================================================
__global__ void split_w_kernel(const float* __restrict__ Wq,
                               const float* __restrict__ Wk,
                               const float* __restrict__ Wv,
                               _Float16* __restrict__ Wf_hi,
                               _Float16* __restrict__ Wf_lo)
{
    int g = blockIdx.x * 256 + threadIdx.x;     // 0..24575
    int nm  = g & 63;
    int kk8 = (g >> 6) & 127;
    int mat = g >> 13;
    const float* W = (mat == 0) ? Wq : (mat == 1) ? Wk : Wv;

    half8_t hi, lo;
    #pragma unroll
    for (int i = 0; i < 8; ++i) {
        float w = W[(kk8 * 8 + i) * 64 + nm];
        _Float16 h = (_Float16)w;
        hi[i] = h;
        lo[i] = (_Float16)(w - (float)h);
    }
    ((half8_t*)Wf_hi)[g] = hi;
    ((half8_t*)Wf_lo)[g] = lo;
}

// ============================================================================
// proj_mfma: f16x3 MFMA projection (validated R4). Epilogue now writes
// q,k as f16 hi/lo (row-major [B*T][64]) and V transposed f16 vt[b][d][t].
// ============================================================================
__global__ __launch_bounds__(256, 2)
void proj_mfma_kernel(const float* __restrict__ x,
                      const _Float16* __restrict__ Wf_hi,
                      const _Float16* __restrict__ Wf_lo,
                      _Float16* __restrict__ qh, _Float16* __restrict__ ql,
                      _Float16* __restrict__ kh, _Float16* __restrict__ kl,
                      _Float16* __restrict__ vt)
{
    __shared__ __align__(16) _Float16 Ah[64 * 72];
    __shared__ __align__(16) _Float16 Al[64 * 72];
    __shared__ __align__(16) _Float16 Bh[4096];
    __shared__ __align__(16) _Float16 Bl[4096];

    const int tid  = threadIdx.x;
    const int lane = tid & 63;
    const int wid  = tid >> 6;
    const int wm   = wid >> 1;
    const int wn   = wid & 1;
    const int l15  = lane & 15;
    const int lg   = lane >> 4;

    const int m0  = blockIdx.x * 64;
    const int mat = blockIdx.y;
    const _Float16* WfhM = Wf_hi + mat * 65536;
    const _Float16* WflM = Wf_lo + mat * 65536;

    f32x4 accM[2][2], accC[2][2];
    #pragma unroll
    for (int a = 0; a < 2; ++a)
        #pragma unroll
        for (int b = 0; b < 2; ++b) {
            accM[a][b] = (f32x4){0.f, 0.f, 0.f, 0.f};
            accC[a][b] = (f32x4){0.f, 0.f, 0.f, 0.f};
        }

    for (int kstep = 0; kstep < 16; ++kstep) {
        const int k0 = kstep * 64;
        __syncthreads();
        #pragma unroll
        for (int j = 0; j < 4; ++j) {
            int f   = tid + j * 256;
            int row = f >> 4;
            int c4  = f & 15;
            float4 xv = *(const float4*)&x[(size_t)(m0 + row) * C_ + k0 + c4 * 4];
            _Float16 hx = (_Float16)xv.x; _Float16 lx = (_Float16)(xv.x - (float)hx);
            _Float16 hy = (_Float16)xv.y; _Float16 ly = (_Float16)(xv.y - (float)hy);
            _Float16 hz = (_Float16)xv.z; _Float16 lz = (_Float16)(xv.z - (float)hz);
            _Float16 hw = (_Float16)xv.w; _Float16 lw = (_Float16)(xv.w - (float)hw);
            int off = row * 72 + c4 * 4;
            *(half4_t*)&Ah[off] = (half4_t){hx, hy, hz, hw};
            *(half4_t*)&Al[off] = (half4_t){lx, ly, lz, lw};
        }
        {
            const uint4* gh = (const uint4*)(WfhM + kstep * 4096);
            const uint4* gl = (const uint4*)(WflM + kstep * 4096);
            #pragma unroll
            for (int j = 0; j < 2; ++j) {
                int f = tid + j * 256;
                *(uint4*)&Bh[f * 8] = gh[f];
                *(uint4*)&Bl[f * 8] = gl[f];
            }
        }
        __syncthreads();

        #pragma unroll
        for (int ks = 0; ks < 2; ++ks) {
            half8_t ah[2], al[2], bh[2], bl[2];
            #pragma unroll
            for (int fm = 0; fm < 2; ++fm) {
                int off = (wm * 32 + fm * 16 + l15) * 72 + ks * 32 + lg * 8;
                ah[fm] = *(const half8_t*)&Ah[off];
                al[fm] = *(const half8_t*)&Al[off];
            }
            #pragma unroll
            for (int fn = 0; fn < 2; ++fn) {
                int off = ((ks * 4 + lg) * 64 + wn * 32 + fn * 16 + l15) * 8;
                bh[fn] = *(const half8_t*)&Bh[off];
                bl[fn] = *(const half8_t*)&Bl[off];
            }
            #pragma unroll
            for (int fm = 0; fm < 2; ++fm)
                #pragma unroll
                for (int fn = 0; fn < 2; ++fn) {
                    accM[fm][fn] = __builtin_amdgcn_mfma_f32_16x16x32_f16(
                        ah[fm], bh[fn], accM[fm][fn], 0, 0, 0);
                    accC[fm][fn] = __builtin_amdgcn_mfma_f32_16x16x32_f16(
                        ah[fm], bl[fn], accC[fm][fn], 0, 0, 0);
                    accC[fm][fn] = __builtin_amdgcn_mfma_f32_16x16x32_f16(
                        al[fm], bh[fn], accC[fm][fn], 0, 0, 0);
                }
        }
    }

    // epilogue: C/D col=lane&15, row=(lane>>4)*4+reg
    #pragma unroll
    for (int fm = 0; fm < 2; ++fm)
        #pragma unroll
        for (int fn = 0; fn < 2; ++fn) {
            const int col = wn * 32 + fn * 16 + l15;
            const int rw0 = m0 + wm * 32 + fm * 16 + lg * 4;
            float vals[4];
            #pragma unroll
            for (int reg = 0; reg < 4; ++reg)
                vals[reg] = accM[fm][fn][reg] + accC[fm][fn][reg];
            if (mat == 2) {
                half4_t pk;
                #pragma unroll
                for (int reg = 0; reg < 4; ++reg) pk[reg] = (_Float16)vals[reg];
                int bb = rw0 >> 12, tt = rw0 & 4095;
                *(half4_t*)&vt[(size_t)bb * 262144 + (size_t)col * 4096 + tt] = pk;
            } else {
                _Float16* oh = mat ? kh : qh;
                _Float16* ol = mat ? kl : ql;
                #pragma unroll
                for (int reg = 0; reg < 4; ++reg) {
                    size_t idx = (size_t)(rw0 + reg) * 64 + col;
                    _Float16 h = (_Float16)vals[reg];
                    oh[idx] = h;
                    ol[idx] = (_Float16)(vals[reg] - (float)h);
                }
            }
        }
}

// ============================================================================
// MFMA flash attention (causal). 256 blocks x 512 thr (8 waves).
// Block = batch b, tile pair {a, 127-a} (32 q-rows each) -> constant work.
// Per tile: 8-way key split over waves (32-key units), per-wave online
// softmax in C-layout, P->f16 via wave-private LDS (stride 40), PV MFMA,
// 3-round LDS merge. Scores use f16 hi/lo Q,K (3-term MFMA, ~fp32-exact).
// ============================================================================
__global__ __launch_bounds__(512, 2)
void attn_mfma_kernel(const _Float16* __restrict__ qh, const _Float16* __restrict__ ql,
                      const _Float16* __restrict__ kh, const _Float16* __restrict__ kl,
                      const _Float16* __restrict__ vt, float* __restrict__ out)
{
    __shared__ __align__(16) float    mergeBuf[4 * 64 * 52];   // 53248 B
    __shared__ __align__(16) _Float16 Plds[8 * 32 * 40];       // 20480 B

    const int tid  = threadIdx.x;
    const int w    = tid >> 6;
    const int lane = tid & 63;
    const int l15  = lane & 15;
    const int lg   = lane >> 4;

    const int b = blockIdx.x >> 6;
    const int a = blockIdx.x & 63;

    _Float16* Pw = Plds + w * (32 * 40);

    for (int hidx = 0; hidx < 2; ++hidx) {
        const int tile = hidx ? (127 - a) : a;
        const int t0   = tile * 32;

        // ---- Q fragments (hi/lo), reused across all kv units ----
        half8_t Qh[2][2], Qlo[2][2];
        #pragma unroll
        for (int fm = 0; fm < 2; ++fm)
            #pragma unroll
            for (int ks = 0; ks < 2; ++ks) {
                size_t off = ((size_t)b * T_ + t0 + fm * 16 + l15) * 64 + ks * 32 + lg * 8;
                Qh[fm][ks]  = *(const half8_t*)&qh[off];
                Qlo[fm][ks] = *(const half8_t*)&ql[off];
            }

        f32x4 O[2][4];
        float rm[2][4], rl[2][4];
        #pragma unroll
        for (int fm = 0; fm < 2; ++fm) {
            #pragma unroll
            for (int fn = 0; fn < 4; ++fn) O[fm][fn] = (f32x4){0.f, 0.f, 0.f, 0.f};
            #pragma unroll
            for (int reg = 0; reg < 4; ++reg) { rm[fm][reg] = -1e30f; rl[fm][reg] = 0.f; }
        }

        const int nkv = tile + 1;
        for (int u = w; u < nkv; u += 8) {
            const int j0 = u * 32;

            // ---- loads first (V too: hides under QK MFMAs) ----
            half8_t Kh_[2][2], Kl_[2][2], VB[4];
            #pragma unroll
            for (int fn = 0; fn < 2; ++fn)
                #pragma unroll
                for (int ks = 0; ks < 2; ++ks) {
                    size_t off = ((size_t)b * T_ + j0 + fn * 16 + l15) * 64 + ks * 32 + lg * 8;
                    Kh_[fn][ks] = *(const half8_t*)&kh[off];
                    Kl_[fn][ks] = *(const half8_t*)&kl[off];
                }
            #pragma unroll
            for (int fn = 0; fn < 4; ++fn) {
                size_t off = ((size_t)b * 64 + fn * 16 + l15) * T_ + j0 + lg * 8;
                VB[fn] = *(const half8_t*)&vt[off];
            }

            // ---- S = Q K^T (3-term hi/lo) ----
            f32x4 S[2][2];
            #pragma unroll
            for (int fm = 0; fm < 2; ++fm)
                #pragma unroll
                for (int fn = 0; fn < 2; ++fn) {
                    f32x4 acc = (f32x4){0.f, 0.f, 0.f, 0.f};
                    #pragma unroll
                    for (int ks = 0; ks < 2; ++ks) {
                        acc = __builtin_amdgcn_mfma_f32_16x16x32_f16(Qh[fm][ks],  Kh_[fn][ks], acc, 0, 0, 0);
                        acc = __builtin_amdgcn_mfma_f32_16x16x32_f16(Qh[fm][ks],  Kl_[fn][ks], acc, 0, 0, 0);
                        acc = __builtin_amdgcn_mfma_f32_16x16x32_f16(Qlo[fm][ks], Kh_[fn][ks], acc, 0, 0, 0);
                    }
                    S[fm][fn] = acc;
                }

            // ---- scale + causal mask ----
            #pragma unroll
            for (int fm = 0; fm < 2; ++fm)
                #pragma unroll
                for (int fn = 0; fn < 2; ++fn)
                    #pragma unroll
                    for (int reg = 0; reg < 4; ++reg) {
                        int key = j0 + fn * 16 + l15;
                        int row = t0 + fm * 16 + lg * 4 + reg;
                        float sv = S[fm][fn][reg] * 0.125f;
                        S[fm][fn][reg] = (key <= row) ? sv : -1e30f;
                    }

            // ---- row max (within lane over fn, then 16-lane butterfly) ----
            float fs[2][4];
            #pragma unroll
            for (int fm = 0; fm < 2; ++fm)
                #pragma unroll
                for (int reg = 0; reg < 4; ++reg) {
                    float x = fmaxf(S[fm][0][reg], S[fm][1][reg]);
                    x = fmaxf(x, __shfl_xor(x, 1));
                    x = fmaxf(x, __shfl_xor(x, 2));
                    x = fmaxf(x, __shfl_xor(x, 4));
                    x = fmaxf(x, __shfl_xor(x, 8));
                    float mn = fmaxf(rm[fm][reg], x);
                    float f  = __expf(rm[fm][reg] - mn);
                    rm[fm][reg] = mn;
                    rl[fm][reg] *= f;
                    fs[fm][reg] = f;
                }
            #pragma unroll
            for (int fm = 0; fm < 2; ++fm)
                #pragma unroll
                for (int fn = 0; fn < 4; ++fn)
                    #pragma unroll
                    for (int reg = 0; reg < 4; ++reg)
                        O[fm][fn][reg] *= fs[fm][reg];

            // ---- P = exp(S - m); row sum ----
            #pragma unroll
            for (int fm = 0; fm < 2; ++fm)
                #pragma unroll
                for (int fn = 0; fn < 2; ++fn)
                    #pragma unroll
                    for (int reg = 0; reg < 4; ++reg)
                        S[fm][fn][reg] = __expf(S[fm][fn][reg] - rm[fm][reg]);
            #pragma unroll
            for (int fm = 0; fm < 2; ++fm)
                #pragma unroll
                for (int reg = 0; reg < 4; ++reg) {
                    float ps = S[fm][0][reg] + S[fm][1][reg];
                    ps += __shfl_xor(ps, 1);
                    ps += __shfl_xor(ps, 2);
                    ps += __shfl_xor(ps, 4);
                    ps += __shfl_xor(ps, 8);
                    rl[fm][reg] += ps;
                }

            // ---- P -> f16 -> wave-private LDS (row stride 40 halfs) ----
            #pragma unroll
            for (int fm = 0; fm < 2; ++fm)
                #pragma unroll
                for (int fn = 0; fn < 2; ++fn)
                    #pragma unroll
                    for (int reg = 0; reg < 4; ++reg)
                        Pw[(fm * 16 + lg * 4 + reg) * 40 + fn * 16 + l15] =
                            (_Float16)S[fm][fn][reg];
            asm volatile("s_waitcnt lgkmcnt(0)" ::: "memory");
            __builtin_amdgcn_sched_barrier(0);

            // ---- PV ----
            half8_t PA[2];
            #pragma unroll
            for (int fm = 0; fm < 2; ++fm)
                PA[fm] = *(const half8_t*)&Pw[(fm * 16 + l15) * 40 + lg * 8];
            #pragma unroll
            for (int fm = 0; fm < 2; ++fm)
                #pragma unroll
                for (int fn = 0; fn < 4; ++fn)
                    O[fm][fn] = __builtin_amdgcn_mfma_f32_16x16x32_f16(
                        PA[fm], VB[fn], O[fm][fn], 0, 0, 0);
        }

        // ---- 3-round lane-wise merge through LDS ----
        #pragma unroll
        for (int step = 4; step >= 1; step >>= 1) {
            if (w >= step && w < 2 * step) {
                float* dst = &mergeBuf[(size_t)((w - step) * 64 + lane) * 52];
                #pragma unroll
                for (int fm = 0; fm < 2; ++fm)
                    #pragma unroll
                    for (int fn = 0; fn < 4; ++fn)
                        *(f32x4*)&dst[(fm * 4 + fn) * 4] = O[fm][fn];
                #pragma unroll
                for (int fm = 0; fm < 2; ++fm)
                    #pragma unroll
                    for (int reg = 0; reg < 4; ++reg) {
                        dst[32 + fm * 4 + reg] = rm[fm][reg];
                        dst[40 + fm * 4 + reg] = rl[fm][reg];
                    }
            }
            __syncthreads();
            if (w < step) {
                const float* src = &mergeBuf[(size_t)(w * 64 + lane) * 52];
                float w1[2][4], w2[2][4];
                #pragma unroll
                for (int fm = 0; fm < 2; ++fm)
                    #pragma unroll
                    for (int reg = 0; reg < 4; ++reg) {
                        float m2 = src[32 + fm * 4 + reg];
                        float l2 = src[40 + fm * 4 + reg];
                        float M  = fmaxf(rm[fm][reg], m2);
                        w1[fm][reg] = __expf(rm[fm][reg] - M);
                        w2[fm][reg] = __expf(m2 - M);
                        rl[fm][reg] = w1[fm][reg] * rl[fm][reg] + w2[fm][reg] * l2;
                        rm[fm][reg] = M;
                    }
                #pragma unroll
                for (int fm = 0; fm < 2; ++fm)
                    #pragma unroll
                    for (int fn = 0; fn < 4; ++fn) {
                        f32x4 o2 = *(const f32x4*)&src[(fm * 4 + fn) * 4];
                        #pragma unroll
                        for (int reg = 0; reg < 4; ++reg)
                            O[fm][fn][reg] = w1[fm][reg] * O[fm][fn][reg]
                                           + w2[fm][reg] * o2[reg];
                    }
            }
            __syncthreads();
        }

        if (w == 0) {
            float inv[2][4];
            #pragma unroll
            for (int fm = 0; fm < 2; ++fm)
                #pragma unroll
                for (int reg = 0; reg < 4; ++reg)
                    inv[fm][reg] = 1.0f / rl[fm][reg];
            #pragma unroll
            for (int fm = 0; fm < 2; ++fm)
                #pragma unroll
                for (int fn = 0; fn < 4; ++fn)
                    #pragma unroll
                    for (int reg = 0; reg < 4; ++reg)
                        out[((size_t)b * T_ + t0 + fm * 16 + lg * 4 + reg) * 64
                            + fn * 16 + l15] = O[fm][fn][reg] * inv[fm][reg];
        }
        __syncthreads();   // protect merge buffers before next tile
    }
}

extern "C" void kernel_launch(void* const* d_in, const int* in_sizes, int n_in,
                              void* d_out, int out_size, void* d_ws, size_t ws_size,
                              hipStream_t stream) {
    const float* x  = (const float*)d_in[0];
    const float* Wq = (const float*)d_in[1];
    const float* Wk = (const float*)d_in[2];
    const float* Wv = (const float*)d_in[3];
    float* out = (float*)d_out;

    _Float16* Wf_hi = (_Float16*)d_ws;          // 196608
    _Float16* Wf_lo = Wf_hi + 196608;           // 196608
    _Float16* qh = Wf_lo + 196608;              // 1048576 each
    _Float16* ql = qh + 1048576;
    _Float16* kh = ql + 1048576;
    _Float16* kl = kh + 1048576;
    _Float16* vt = kl + 1048576;

    split_w_kernel<<<96, 256, 0, stream>>>(Wq, Wk, Wv, Wf_hi, Wf_lo);
    dim3 gp(B_ * T_ / 64, 3);
    proj_mfma_kernel<<<gp, 256, 0, stream>>>(x, Wf_hi, Wf_lo, qh, ql, kh, kl, vt);
    attn_mfma_kernel<<<256, 512, 0, stream>>>(qh, ql, kh, kl, vt, out);
}